// Round 7
// baseline (1067.028 us; speedup 1.0000x reference)
//
#include <hip/hip_runtime.h>
#include <math.h>

// GatedSpikingReservoirStep — fp16 MFMA fused kernel, software-pipelined.
// Round 7: round-6 fused_step was latency-bound (MfmaUtil 10%, VALUBusy 11%,
// ~1300 cyc/iter vs ~250 compute): the [issue; sync; compute; sync] K-loop
// exposes full vmem latency every iteration. New structure: double-buffered
// LDS, ONE barrier/iter, prefetch of chunk v+1 issued right after the barrier
// so its latency hides under compute of chunk v. BK=64 (24 KB/iter in
// flight), XOR swizzle over 8 chunks/row (2-way = free). LDS 48 KB ->
// 3 blocks/CU. Pipe floor: 48 ds_read_b128/block-iter -> ~61 us LDS-bound.
// Numerics unchanged from round 6 (fp16 single, band 4e-3, fp64 fixup).

#define IDIM 512
#define DDIM 2048
#define MAXD 2560
#define BDIM 4096
#define LIST_CAP 262144
#define BAND 4e-3f

typedef __attribute__((ext_vector_type(4))) float f32x4;
typedef __attribute__((ext_vector_type(8))) _Float16 f16x8;

__device__ __forceinline__ void gld16(const unsigned short* g, unsigned short* l) {
    __builtin_amdgcn_global_load_lds((const __attribute__((address_space(1))) void*)g,
                                     (__attribute__((address_space(3))) void*)l,
                                     16, 0, 0);
}
__device__ __forceinline__ float sigf(float x) { return 1.0f / (1.0f + __expf(-x)); }

// ---------------------------------------------------------------------------
// convert: fp32 -> fp16 for X, S=state[:, :2048], Wc=[Win;Wgate], Wr;
// zero out-pad; zero fixup counter.
// ---------------------------------------------------------------------------
__global__ __launch_bounds__(256) void convert_kernel(
    const float* __restrict__ x, const float* __restrict__ state,
    const float* __restrict__ win, const float* __restrict__ wgate,
    const float* __restrict__ wres,
    unsigned short* __restrict__ X16, unsigned short* __restrict__ S16,
    unsigned short* __restrict__ Wc16, unsigned short* __restrict__ Wr16,
    float* __restrict__ out, unsigned* __restrict__ cnt)
{
    int idx = blockIdx.x * 256 + threadIdx.x;
    if (idx == 0) *cnt = 0u;
    float4 v;
    unsigned short* p;
    long off;
    if (idx < 524288) {
        v = ((const float4*)x)[idx];
        p = X16; off = (long)idx * 4;
    } else if (idx < 2621440) {
        int i = idx - 524288;
        int row = i >> 9, c4 = i & 511;
        v = *(const float4*)(state + (long)row * MAXD + c4 * 4);
        p = S16; off = (long)i * 4;
    } else if (idx < 3670016) {
        int i = idx - 2621440;
        v = (i < 262144) ? ((const float4*)win)[i] : ((const float4*)wgate)[i - 262144];
        p = Wc16; off = (long)i * 4;
    } else if (idx < 4718592) {
        int i = idx - 3670016;
        v = ((const float4*)wres)[i];
        p = Wr16; off = (long)i * 4;
    } else {
        int i = idx - 4718592;
        int row = i >> 7, c4 = i & 127;
        *(float4*)(out + (long)row * MAXD + DDIM + c4 * 4) = make_float4(0.f, 0.f, 0.f, 0.f);
        return;
    }
    _Float16 h0 = (_Float16)v.x, h1 = (_Float16)v.y;
    _Float16 h2 = (_Float16)v.z, h3 = (_Float16)v.w;
    ushort4 hv;
    hv.x = *(unsigned short*)&h0; hv.y = *(unsigned short*)&h1;
    hv.z = *(unsigned short*)&h2; hv.w = *(unsigned short*)&h3;
    *(ushort4*)(p + off) = hv;
}

// ---------------------------------------------------------------------------
// fused_step: 5 GEMM phases as 64 virtual BK=64 iterations, pipelined dbuf.
// Block tile 128x64, 4 waves (2x2), wave tile 64x32.
// LDS layout: row r (64 halves = 8 chunks of 16B), chunk c stored at slot
// c ^ (r&7)  -> ds_read_b128 2-way bank aliasing (free), and legal
// global_load_lds lane scatter (lane = row_off*8 + slot).
// ---------------------------------------------------------------------------
__global__ __launch_bounds__(256, 3) void fused_step(
    const unsigned short* __restrict__ X16, const unsigned short* __restrict__ S16,
    const unsigned short* __restrict__ Wc16, const unsigned short* __restrict__ Wr16,
    const float* __restrict__ state, float* __restrict__ out,
    unsigned* __restrict__ cnt, unsigned* __restrict__ list)
{
    __shared__ alignas(16) unsigned short lsA[2][128 * 64];  // 2 x 16 KB
    __shared__ alignas(16) unsigned short lsB[2][64 * 64];   // 2 x  8 KB
    const int t = threadIdx.x;
    const int wave = t >> 6, lane = t & 63;
    const int wr = wave >> 1, wcl = wave & 1;
    const int quad = lane >> 4, l16 = lane & 15;
    const int m0 = blockIdx.y * 128;
    const int n0 = blockIdx.x * 64;
    // staging lane mapping
    const int row_off = lane >> 3;            // 0..7
    const int slot = lane & 7;                // LDS slot this lane fills
    const int kc = slot ^ row_off;            // global 16B chunk it must fetch
    const long laneD = (long)row_off * DDIM + kc * 8;
    const long laneI = (long)row_off * IDIM + kc * 8;
    // read-side swizzled slot for ksub0 (ksub1 = ^4 -> half-offset ^32)
    const int s0h = (quad ^ (l16 & 7)) * 8;

    const unsigned short* Abase_s = S16 + (long)m0 * DDIM;
    const unsigned short* Abase_x = X16 + (long)m0 * IDIM;
    const unsigned short* Bbase_r = Wr16 + (long)n0 * DDIM;

    f32x4 acc[4][2];
    f32x4 tv[4][2];
    f32x4 ft[4][2];
    #pragma unroll
    for (int mi = 0; mi < 4; mi++)
        #pragma unroll
        for (int ni = 0; ni < 2; ni++)
            acc[mi][ni] = (f32x4)0.0f;

    auto issue = [&](int v, int bi) {
        const unsigned short* Ab; const unsigned short* Bb;
        long ldA, ldB, lA, lB; int k0;
        if (v < 32) {
            Ab = Abase_s; ldA = DDIM; lA = laneD;
            Bb = Bbase_r; ldB = DDIM; lB = laneD;
            k0 = v * 64;
        } else {
            int seg = (v - 32) >> 3;
            Ab = Abase_x; ldA = IDIM; lA = laneI;
            Bb = Wc16 + (long)(seg * DDIM + n0) * IDIM; ldB = IDIM; lB = laneI;
            k0 = (v & 7) * 64;
        }
        unsigned short* dA = &lsA[bi][wave * 2048];
        unsigned short* dB = &lsB[bi][wave * 1024];
        const unsigned short* ga = Ab + (long)(wave * 32) * ldA + lA + k0;
        #pragma unroll
        for (int g = 0; g < 4; g++) gld16(ga + (long)(g * 8) * ldA, dA + g * 512);
        const unsigned short* gb = Bb + (long)(wave * 16) * ldB + lB + k0;
        #pragma unroll
        for (int g = 0; g < 2; g++) gld16(gb + (long)(g * 8) * ldB, dB + g * 512);
    };

    auto compute = [&](int bi) {
        #pragma unroll
        for (int ks = 0; ks < 2; ks++) {
            f16x8 af[4], bf[2];
            const int kx = ks ? (s0h ^ 32) : s0h;
            #pragma unroll
            for (int mi = 0; mi < 4; mi++)
                af[mi] = *(const f16x8*)&lsA[bi][(wr * 64 + mi * 16 + l16) * 64 + kx];
            #pragma unroll
            for (int ni = 0; ni < 2; ni++)
                bf[ni] = *(const f16x8*)&lsB[bi][(wcl * 32 + ni * 16 + l16) * 64 + kx];
            #pragma unroll
            for (int mi = 0; mi < 4; mi++)
                #pragma unroll
                for (int ni = 0; ni < 2; ni++)
                    acc[mi][ni] = __builtin_amdgcn_mfma_f32_16x16x32_f16(af[mi], bf[ni], acc[mi][ni], 0, 0, 0);
        }
    };

    issue(0, 0);
    #pragma unroll 1
    for (int v = 0; v < 64; v++) {
        __syncthreads();                      // drains chunk-v loads (vmcnt 0)
        if (v < 63) issue(v + 1, (v + 1) & 1);  // prefetch under compute
        compute(v & 1);
        if (v == 39) {                        // end of (rp + ip) accumulation
            #pragma unroll
            for (int mi = 0; mi < 4; mi++)
                #pragma unroll
                for (int ni = 0; ni < 2; ni++) { tv[mi][ni] = acc[mi][ni]; acc[mi][ni] = (f32x4)0.0f; }
        } else if (v == 47) {                 // i-gate
            #pragma unroll
            for (int mi = 0; mi < 4; mi++)
                #pragma unroll
                for (int ni = 0; ni < 2; ni++) {
                    #pragma unroll
                    for (int r = 0; r < 4; r++) tv[mi][ni][r] = sigf(acc[mi][ni][r]) * tv[mi][ni][r];
                    acc[mi][ni] = (f32x4)0.0f;
                }
        } else if (v == 55) {                 // f-gate
            #pragma unroll
            for (int mi = 0; mi < 4; mi++)
                #pragma unroll
                for (int ni = 0; ni < 2; ni++) {
                    #pragma unroll
                    for (int r = 0; r < 4; r++) {
                        int row = m0 + wr * 64 + mi * 16 + quad * 4 + r;
                        int col = n0 + wcl * 32 + ni * 16 + l16;
                        float prev = state[(long)row * MAXD + col];
                        ft[mi][ni][r] = 0.8f * sigf(acc[mi][ni][r]) * prev;
                    }
                    acc[mi][ni] = (f32x4)0.0f;
                }
        }
    }

    // epilogue: acc = o-gate logits
    #pragma unroll
    for (int mi = 0; mi < 4; mi++)
        #pragma unroll
        for (int ni = 0; ni < 2; ni++) {
            #pragma unroll
            for (int r = 0; r < 4; r++) {
                int row = m0 + wr * 64 + mi * 16 + quad * 4 + r;
                int col = n0 + wcl * 32 + ni * 16 + l16;
                float go = sigf(acc[mi][ni][r]);
                float ns = go * (ft[mi][ni][r] + 0.2f * tanhf(tv[mi][ni][r]));
                float ov = (ns > 0.5f) ? ns - 0.5f : ns;
                out[(long)row * MAXD + col] = ov;
                if (fabsf(ns - 0.5f) < BAND) {
                    unsigned pos = atomicAdd(cnt, 1u);
                    if (pos < LIST_CAP) list[pos] = (unsigned)(row * DDIM + col);
                }
            }
        }
}

// ---------------------------------------------------------------------------
// fixup: recompute flagged elements exactly in fp64 (inputs are L3-resident).
// ---------------------------------------------------------------------------
__global__ __launch_bounds__(256) void fixup_kernel(
    const float* __restrict__ x, const float* __restrict__ state,
    const float* __restrict__ win, const float* __restrict__ wres,
    const float* __restrict__ wgate,
    const unsigned* __restrict__ cnt, const unsigned* __restrict__ list,
    float* __restrict__ out)
{
    const int gwave = (blockIdx.x * 256 + threadIdx.x) >> 6;
    const int lane = threadIdx.x & 63;
    const int nwaves = gridDim.x * 4;
    unsigned n = *cnt;
    if (n > LIST_CAP) n = LIST_CAP;
    for (unsigned e = gwave; e < n; e += nwaves) {
        unsigned rc = list[e];
        int row = rc >> 11, col = rc & 2047;
        double ip = 0.0, gi = 0.0, gf = 0.0, go = 0.0, rp = 0.0;
        for (int k = lane; k < IDIM; k += 64) {
            double xv = (double)x[(long)row * IDIM + k];
            ip += xv * (double)win[(long)col * IDIM + k];
            gi += xv * (double)wgate[(long)col * IDIM + k];
            gf += xv * (double)wgate[(long)(DDIM + col) * IDIM + k];
            go += xv * (double)wgate[(long)(2 * DDIM + col) * IDIM + k];
        }
        for (int k = lane; k < DDIM; k += 64) {
            rp += (double)state[(long)row * MAXD + k] * (double)wres[(long)col * DDIM + k];
        }
        #pragma unroll
        for (int o = 32; o > 0; o >>= 1) {
            ip += __shfl_down(ip, o);
            gi += __shfl_down(gi, o);
            gf += __shfl_down(gf, o);
            go += __shfl_down(go, o);
            rp += __shfl_down(rp, o);
        }
        if (lane == 0) {
            double si = 1.0 / (1.0 + exp(-gi));
            double sf = 1.0 / (1.0 + exp(-gf));
            double so = 1.0 / (1.0 + exp(-go));
            double prev = (double)state[(long)row * MAXD + col];
            double ns = so * (0.8 * sf * prev + 0.2 * tanh(si * (ip + rp)));
            if (ns > 0.5) ns -= 0.5;
            out[(long)row * MAXD + col] = (float)ns;
        }
    }
}

extern "C" void kernel_launch(void* const* d_in, const int* in_sizes, int n_in,
                              void* d_out, int out_size, void* d_ws, size_t ws_size,
                              hipStream_t stream) {
    const float* x     = (const float*)d_in[0];   // (4096, 512)
    const float* state = (const float*)d_in[1];   // (4096, 2560)
    const float* win   = (const float*)d_in[2];   // (2048, 512)
    const float* wres  = (const float*)d_in[3];   // (2048, 2048)
    const float* wgate = (const float*)d_in[4];   // (6144, 512)
    float* out = (float*)d_out;

    char* ws = (char*)d_ws;
    unsigned short* X16  = (unsigned short*)(ws);                   //  0.. 4 MiB
    unsigned short* S16  = (unsigned short*)(ws + (4ll  << 20));    //  4..20
    unsigned short* Wc16 = (unsigned short*)(ws + (20ll << 20));    // 20..28
    unsigned short* Wr16 = (unsigned short*)(ws + (28ll << 20));    // 28..36
    unsigned* cnt  = (unsigned*)(ws + (36ll << 20));                // 4 B
    unsigned* list = (unsigned*)(ws + (36ll << 20) + 16);           // 1 MiB

    convert_kernel<<<dim3(20480), dim3(256), 0, stream>>>(
        x, state, win, wgate, wres, X16, S16, Wc16, Wr16, out, cnt);

    fused_step<<<dim3(32, 32), dim3(256), 0, stream>>>(
        X16, S16, Wc16, Wr16, state, out, cnt, list);

    fixup_kernel<<<dim3(512), dim3(256), 0, stream>>>(
        x, state, win, wres, wgate, cnt, list, out);
}